// Round 1
// baseline (266.995 us; speedup 1.0000x reference)
//
#include <hip/hip_runtime.h>

// PerformerAttention: B=4 H=16 S=4096 D=64, fp32.
//   q = relu(Q)+eps; k = (relu(K)+eps)*mask
//   kv[bh][d][e] = sum_s k[s][d]*v[s][e];  ksum[bh][d] = sum_s k[s][d]
//   out[s][e] = (sum_d q[s][d]*kv[d][e]) / (sum_d q[s][d]*ksum[d])

namespace {
constexpr int kB = 4, kH = 16, kS = 4096, kD = 64;
constexpr int kBH = kB * kH;
constexpr float kEps = 0.001f;

constexpr int CH1 = 8;            // S-chunks, pass 1
constexpr int CS1 = kS / CH1;     // 512 rows / block
constexpr int TS  = 16;           // rows per LDS tile
constexpr int CH2 = 16;           // S-chunks, pass 2
constexpr int CS2 = kS / CH2;     // 256 rows / block

constexpr int KVSZ = kD * kD;     // 4096
constexpr int SEG  = KVSZ + kD;   // 4160 floats per segment (kv + ksum)
}

// ---------------- Pass 1: partial kv + ksum per (bh, chunk) ----------------
__global__ __launch_bounds__(256)
void pa_kv_partial(const float* __restrict__ key, const float* __restrict__ value,
                   const float* __restrict__ mask, float* __restrict__ P) {
  const int bh    = blockIdx.x / CH1;
  const int chunk = blockIdx.x - bh * CH1;
  const int b     = bh / kH;
  const int s0    = chunk * CS1;
  const float* kbase = key   + (size_t)bh * kS * kD;
  const float* vbase = value + (size_t)bh * kS * kD;
  const float* mbase = mask  + (size_t)b * kS;

  __shared__ float ks[TS][kD];
  __shared__ float vs[TS][kD];

  const int tid  = threadIdx.x;
  const int ti   = tid >> 4;    // 0..15: owns d rows 4*ti..4*ti+3 (and loads tile row ti)
  const int tj   = tid & 15;    // 0..15: owns e cols 4*tj..4*tj+3
  const int lcol = tj << 2;

  float acc[4][4];
#pragma unroll
  for (int r = 0; r < 4; ++r)
#pragma unroll
    for (int c = 0; c < 4; ++c) acc[r][c] = 0.f;
  float ksx = 0.f, ksy = 0.f, ksz = 0.f, ksw = 0.f;

  // software-pipelined prefetch of tile 0
  float4 kq = *(const float4*)(kbase + ((size_t)(s0 + ti)) * kD + lcol);
  float4 vq = *(const float4*)(vbase + ((size_t)(s0 + ti)) * kD + lcol);
  float  m  = mbase[s0 + ti];

  for (int t = 0; t < CS1; t += TS) {
    float4 kt;
    kt.x = (fmaxf(kq.x, 0.f) + kEps) * m;
    kt.y = (fmaxf(kq.y, 0.f) + kEps) * m;
    kt.z = (fmaxf(kq.z, 0.f) + kEps) * m;
    kt.w = (fmaxf(kq.w, 0.f) + kEps) * m;
    float4 vt = vq;

    __syncthreads();
    *(float4*)&ks[ti][lcol] = kt;
    *(float4*)&vs[ti][lcol] = vt;
    ksx += kt.x; ksy += kt.y; ksz += kt.z; ksw += kt.w;
    __syncthreads();

    if (t + TS < CS1) {               // issue next tile's loads; awaited next iter
      const int sn = s0 + t + TS + ti;
      kq = *(const float4*)(kbase + (size_t)sn * kD + lcol);
      vq = *(const float4*)(vbase + (size_t)sn * kD + lcol);
      m  = mbase[sn];
    }

#pragma unroll
    for (int ss = 0; ss < TS; ++ss) {
      const float4 kf = *(const float4*)&ks[ss][ti << 2];
      const float4 vf = *(const float4*)&vs[ss][tj << 2];
      acc[0][0] = fmaf(kf.x, vf.x, acc[0][0]);
      acc[0][1] = fmaf(kf.x, vf.y, acc[0][1]);
      acc[0][2] = fmaf(kf.x, vf.z, acc[0][2]);
      acc[0][3] = fmaf(kf.x, vf.w, acc[0][3]);
      acc[1][0] = fmaf(kf.y, vf.x, acc[1][0]);
      acc[1][1] = fmaf(kf.y, vf.y, acc[1][1]);
      acc[1][2] = fmaf(kf.y, vf.z, acc[1][2]);
      acc[1][3] = fmaf(kf.y, vf.w, acc[1][3]);
      acc[2][0] = fmaf(kf.z, vf.x, acc[2][0]);
      acc[2][1] = fmaf(kf.z, vf.y, acc[2][1]);
      acc[2][2] = fmaf(kf.z, vf.z, acc[2][2]);
      acc[2][3] = fmaf(kf.z, vf.w, acc[2][3]);
      acc[3][0] = fmaf(kf.w, vf.x, acc[3][0]);
      acc[3][1] = fmaf(kf.w, vf.y, acc[3][1]);
      acc[3][2] = fmaf(kf.w, vf.z, acc[3][2]);
      acc[3][3] = fmaf(kf.w, vf.w, acc[3][3]);
    }
  }

  // write kv partial
  float* Pd = P + ((size_t)bh * CH1 + chunk) * SEG;
#pragma unroll
  for (int r = 0; r < 4; ++r) {
    float4 o = make_float4(acc[r][0], acc[r][1], acc[r][2], acc[r][3]);
    *(float4*)&Pd[(size_t)(4 * ti + r) * kD + 4 * tj] = o;
  }

  // reduce per-thread ksum partials across tile rows via LDS (reuse ks)
  __syncthreads();
  ks[ti][lcol + 0] = ksx;
  ks[ti][lcol + 1] = ksy;
  ks[ti][lcol + 2] = ksz;
  ks[ti][lcol + 3] = ksw;
  __syncthreads();
  if (tid < kD) {
    float tot = 0.f;
#pragma unroll
    for (int r = 0; r < TS; ++r) tot += ks[r][tid];
    Pd[KVSZ + tid] = tot;
  }
}

// ---------------- Pass 1.5: reduce chunk partials ----------------
__global__ __launch_bounds__(256)
void pa_reduce(const float* __restrict__ P, float* __restrict__ R) {
  const int gid = blockIdx.x * 256 + threadIdx.x;
  const int o = gid * 4;
  if (o >= kBH * SEG) return;
  const int bh  = o / SEG;
  const int pos = o - bh * SEG;
  const float* base = P + (size_t)bh * CH1 * SEG + pos;
  float ax = 0.f, ay = 0.f, az = 0.f, aw = 0.f;
#pragma unroll
  for (int c = 0; c < CH1; ++c) {
    const float4 t = *(const float4*)(base + (size_t)c * SEG);
    ax += t.x; ay += t.y; az += t.z; aw += t.w;
  }
  *(float4*)&R[o] = make_float4(ax, ay, az, aw);
}

// ---------------- Pass 2: out = (q . kv) / (q . ksum) ----------------
__global__ __launch_bounds__(256)
void pa_out(const float* __restrict__ query, const float* __restrict__ R,
            float* __restrict__ out) {
  const int bh    = blockIdx.x / CH2;
  const int chunk = blockIdx.x - bh * CH2;
  const int s     = chunk * CS2 + threadIdx.x;

  __shared__ float kvs[KVSZ];   // 16 KiB
  __shared__ float ksums[kD];

  const float* Rb = R + (size_t)bh * SEG;
#pragma unroll
  for (int it = 0; it < 4; ++it) {
    const int idx = (threadIdx.x + it * 256) * 4;
    *(float4*)&kvs[idx] = *(const float4*)&Rb[idx];
  }
  if (threadIdx.x < kD) ksums[threadIdx.x] = Rb[KVSZ + threadIdx.x];
  __syncthreads();

  const float* qrow = query + ((size_t)bh * kS + s) * kD;
  float q[kD];
#pragma unroll
  for (int d4 = 0; d4 < kD / 4; ++d4) {
    const float4 t = *(const float4*)(qrow + d4 * 4);
    q[d4 * 4 + 0] = fmaxf(t.x, 0.f) + kEps;
    q[d4 * 4 + 1] = fmaxf(t.y, 0.f) + kEps;
    q[d4 * 4 + 2] = fmaxf(t.z, 0.f) + kEps;
    q[d4 * 4 + 3] = fmaxf(t.w, 0.f) + kEps;
  }

  float den = 0.f;
#pragma unroll
  for (int d = 0; d < kD; ++d) den = fmaf(q[d], ksums[d], den);
  const float invden = 1.0f / den;

  float* orow = out + ((size_t)bh * kS + s) * kD;
  for (int e4 = 0; e4 < kD / 4; ++e4) {   // rolled: keeps I-footprint small
    float ax = 0.f, ay = 0.f, az = 0.f, aw = 0.f;
#pragma unroll
    for (int d = 0; d < kD; ++d) {
      const float4 kvv = *(const float4*)&kvs[d * kD + e4 * 4];  // uniform addr -> broadcast
      ax = fmaf(q[d], kvv.x, ax);
      ay = fmaf(q[d], kvv.y, ay);
      az = fmaf(q[d], kvv.z, az);
      aw = fmaf(q[d], kvv.w, aw);
    }
    *(float4*)&orow[e4 * 4] = make_float4(ax * invden, ay * invden, az * invden, aw * invden);
  }
}

extern "C" void kernel_launch(void* const* d_in, const int* in_sizes, int n_in,
                              void* d_out, int out_size, void* d_ws, size_t ws_size,
                              hipStream_t stream) {
  const float* query = (const float*)d_in[0];
  const float* key   = (const float*)d_in[1];
  const float* value = (const float*)d_in[2];
  const float* mask  = (const float*)d_in[3];
  float* outp = (float*)d_out;

  float* P = (float*)d_ws;                        // kBH*CH1*SEG floats (~8.5 MB)
  float* R = P + (size_t)kBH * CH1 * SEG;         // kBH*SEG floats (~1 MB)

  hipLaunchKernelGGL(pa_kv_partial, dim3(kBH * CH1), dim3(256), 0, stream,
                     key, value, mask, P);
  hipLaunchKernelGGL(pa_reduce, dim3((kBH * SEG / 4 + 255) / 256), dim3(256), 0, stream,
                     P, R);
  hipLaunchKernelGGL(pa_out, dim3(kBH * CH2), dim3(256), 0, stream,
                     query, R, outp);
}

// Round 2
// 255.662 us; speedup vs baseline: 1.0443x; 1.0443x over previous
//
#include <hip/hip_runtime.h>

// PerformerAttention: B=4 H=16 S=4096 D=64, fp32.
//   q = relu(Q)+eps; k = (relu(K)+eps)*mask
//   kv[bh][d][e] = sum_s k[s][d]*v[s][e];  ksum[bh][d] = sum_s k[s][d]
//   out[s][e] = (sum_d q[s][d]*kv[d][e]) / (sum_d q[s][d]*ksum[d])
//
// Pass 1: per-wave 8x8 register tile over 8-row LDS stages (barrier-free,
//         wave-synchronous), coalesced register->global partial stores.
// Reduce: sums wave partials, un-permutes to natural [d][e] layout.
// Pass 2: kv via wave-uniform scalar loads (SGPR broadcast), full-row acc,
//         LDS-staged fully-coalesced output stores.

namespace {
constexpr int kB = 4, kH = 16, kS = 4096, kD = 64;
constexpr int kBH = kB * kH;
constexpr float kEps = 0.001f;

constexpr int KVSZ = kD * kD;     // 4096 floats
constexpr int SEG  = KVSZ + kD;   // 4160 floats per partial segment (kv + ksum)
constexpr int F4PS = SEG / 4;     // 1040 float4 per segment
}

// ---------------- Pass 1: partial kv + ksum, one segment per wave ----------
__global__ __launch_bounds__(256, 2)
void pa_kv_partial(const float* __restrict__ key, const float* __restrict__ value,
                   const float* __restrict__ mask, float* __restrict__ P, int ch1) {
  __shared__ float smem[4096];   // 4 waves x (ks 512 + vs 512) = 16 KiB

  const int tid  = threadIdx.x;
  const int wid  = tid >> 6;
  const int lane = tid & 63;

  const int bh    = blockIdx.x / ch1;
  const int chunk = blockIdx.x - bh * ch1;
  const int b     = bh >> 4;                 // kH = 16
  const int rows  = kS / ch1;
  const int s0    = chunk * rows;
  const int tiles = rows >> 5;               // 8-row tiles, strided by 4 waves

  const float* kb = key   + (size_t)bh * kS * kD;
  const float* vb = value + (size_t)bh * kS * kD;
  const float* mb = mask  + (size_t)b * kS;

  float* ksT = smem + wid * 1024;            // 8 x 64
  float* vsT = smem + wid * 1024 + 512;      // 8 x 64

  const int lrow = lane >> 4;                // 0..3   (load map)
  const int lcol = (lane & 15) << 2;         // 0..60
  const int ti   = lane >> 3;                // 0..7   (compute map: d rows 8*ti..)
  const int tj   = lane & 7;                 // 0..7   (e cols 8*tj..)

  float acc[8][8];
#pragma unroll
  for (int i = 0; i < 8; ++i)
#pragma unroll
    for (int j = 0; j < 8; ++j) acc[i][j] = 0.f;
  float4 ksacc = make_float4(0.f, 0.f, 0.f, 0.f);

  // prefetch tile 0 for this wave
  int ts = s0 + wid * 8;
  float4 kq0 = *(const float4*)(kb + (size_t)(ts + lrow) * kD + lcol);
  float4 kq1 = *(const float4*)(kb + (size_t)(ts + 4 + lrow) * kD + lcol);
  float4 vq0 = *(const float4*)(vb + (size_t)(ts + lrow) * kD + lcol);
  float4 vq1 = *(const float4*)(vb + (size_t)(ts + 4 + lrow) * kD + lcol);
  float  m0  = mb[ts + lrow];
  float  m1  = mb[ts + 4 + lrow];

  for (int t = 0; t < tiles; ++t) {
    float4 kt0, kt1;
    kt0.x = (fmaxf(kq0.x, 0.f) + kEps) * m0;
    kt0.y = (fmaxf(kq0.y, 0.f) + kEps) * m0;
    kt0.z = (fmaxf(kq0.z, 0.f) + kEps) * m0;
    kt0.w = (fmaxf(kq0.w, 0.f) + kEps) * m0;
    kt1.x = (fmaxf(kq1.x, 0.f) + kEps) * m1;
    kt1.y = (fmaxf(kq1.y, 0.f) + kEps) * m1;
    kt1.z = (fmaxf(kq1.z, 0.f) + kEps) * m1;
    kt1.w = (fmaxf(kq1.w, 0.f) + kEps) * m1;

    ksacc.x += kt0.x + kt1.x;
    ksacc.y += kt0.y + kt1.y;
    ksacc.z += kt0.z + kt1.z;
    ksacc.w += kt0.w + kt1.w;

    // wave-private LDS tile: no block barrier needed (in-order DS, lockstep wave)
    *(float4*)&ksT[lrow * 64 + lcol]       = kt0;
    *(float4*)&ksT[(lrow + 4) * 64 + lcol] = kt1;
    *(float4*)&vsT[lrow * 64 + lcol]       = vq0;
    *(float4*)&vsT[(lrow + 4) * 64 + lcol] = vq1;

    if (t + 1 < tiles) {                    // register prefetch of next tile
      ts += 32;                             // 4 waves x 8 rows
      kq0 = *(const float4*)(kb + (size_t)(ts + lrow) * kD + lcol);
      kq1 = *(const float4*)(kb + (size_t)(ts + 4 + lrow) * kD + lcol);
      vq0 = *(const float4*)(vb + (size_t)(ts + lrow) * kD + lcol);
      vq1 = *(const float4*)(vb + (size_t)(ts + 4 + lrow) * kD + lcol);
      m0  = mb[ts + lrow];
      m1  = mb[ts + 4 + lrow];
    }

#pragma unroll
    for (int ss = 0; ss < 8; ++ss) {
      const float4 kf0 = *(const float4*)&ksT[ss * 64 + 8 * ti];
      const float4 kf1 = *(const float4*)&ksT[ss * 64 + 8 * ti + 4];
      const float4 vf0 = *(const float4*)&vsT[ss * 64 + 8 * tj];
      const float4 vf1 = *(const float4*)&vsT[ss * 64 + 8 * tj + 4];
      const float ka[8] = {kf0.x, kf0.y, kf0.z, kf0.w, kf1.x, kf1.y, kf1.z, kf1.w};
      const float va[8] = {vf0.x, vf0.y, vf0.z, vf0.w, vf1.x, vf1.y, vf1.z, vf1.w};
#pragma unroll
      for (int i = 0; i < 8; ++i)
#pragma unroll
        for (int j = 0; j < 8; ++j) acc[i][j] = fmaf(ka[i], va[j], acc[i][j]);
    }
  }

  // coalesced register->global partial store, permuted layout:
  //   P[seg][f4 index j*64+lane] = kv[8*(lane>>3) + (j>>1)][8*(lane&7) + 4*(j&1) ..]
  float* Pd = P + (size_t)(blockIdx.x * 4 + wid) * SEG;
#pragma unroll
  for (int i = 0; i < 8; ++i)
#pragma unroll
    for (int jj = 0; jj < 2; ++jj) {
      const int j = i * 2 + jj;
      const float4 o = make_float4(acc[i][jj * 4 + 0], acc[i][jj * 4 + 1],
                                   acc[i][jj * 4 + 2], acc[i][jj * 4 + 3]);
      *(float4*)&Pd[(size_t)(j * 64 + lane) * 4] = o;
    }

  // ksum: lane holds column-group partial (col 4*(lane&15)); fold lane>>4 groups
  ksacc.x += __shfl_xor(ksacc.x, 16); ksacc.x += __shfl_xor(ksacc.x, 32);
  ksacc.y += __shfl_xor(ksacc.y, 16); ksacc.y += __shfl_xor(ksacc.y, 32);
  ksacc.z += __shfl_xor(ksacc.z, 16); ksacc.z += __shfl_xor(ksacc.z, 32);
  ksacc.w += __shfl_xor(ksacc.w, 16); ksacc.w += __shfl_xor(ksacc.w, 32);
  if (lane < 16) *(float4*)&Pd[KVSZ + 4 * lane] = ksacc;   // natural d-order
}

// ---------------- Reduce: sum wave partials, un-permute kv -----------------
__global__ __launch_bounds__(256)
void pa_reduce(const float* __restrict__ P, float* __restrict__ R, int nseg) {
  const int gid = blockIdx.x * 256 + threadIdx.x;
  if (gid >= kBH * F4PS) return;
  const int bh  = gid / F4PS;
  const int pos = gid - bh * F4PS;

  const float* base = P + (size_t)bh * nseg * SEG + (size_t)pos * 4;
  float ax = 0.f, ay = 0.f, az = 0.f, aw = 0.f;
  for (int c = 0; c < nseg; ++c) {
    const float4 t = *(const float4*)(base + (size_t)c * SEG);
    ax += t.x; ay += t.y; az += t.z; aw += t.w;
  }

  int dpos;
  if (pos < KVSZ / 4) {          // un-permute to natural [d][e]
    const int j  = pos >> 6, ln = pos & 63;
    const int d  = 8 * (ln >> 3) + (j >> 1);
    const int e4 = 2 * (ln & 7) + (j & 1);
    dpos = d * 16 + e4;
  } else {
    dpos = pos;                  // ksum already natural
  }
  *(float4*)&R[(size_t)bh * SEG + (size_t)dpos * 4] = make_float4(ax, ay, az, aw);
}

// ---------------- Pass 2: out = (q . kv) / (q . ksum) ----------------------
__global__ __launch_bounds__(256)
void pa_out(const float* __restrict__ query, const float* __restrict__ R,
            float* __restrict__ out) {
  __shared__ float ost[64 * 68];   // 64-row output staging, pad 68 (17 KiB)

  const int tid    = threadIdx.x;
  const int bh     = blockIdx.x >> 4;
  const int rowblk = blockIdx.x & 15;
  const int s      = rowblk * 256 + tid;

  const float* qrow = query + ((size_t)bh * kS + s) * kD;
  const float* Rb   = R + (size_t)bh * SEG;   // wave-uniform -> scalar loads

  float4 acc[16];
#pragma unroll
  for (int e = 0; e < 16; ++e) acc[e] = make_float4(0.f, 0.f, 0.f, 0.f);
  float den = 0.f;

#pragma unroll 4
  for (int d4 = 0; d4 < 16; ++d4) {
    const float4 qv = *(const float4*)(qrow + 4 * d4);
    const float qd[4] = {fmaxf(qv.x, 0.f) + kEps, fmaxf(qv.y, 0.f) + kEps,
                         fmaxf(qv.z, 0.f) + kEps, fmaxf(qv.w, 0.f) + kEps};
#pragma unroll
    for (int dd = 0; dd < 4; ++dd) {
      const int d = 4 * d4 + dd;
      den = fmaf(qd[dd], Rb[KVSZ + d], den);
      const float* kvr = Rb + d * 64;          // uniform row -> SGPR broadcast
#pragma unroll
      for (int e = 0; e < 16; ++e) {
        acc[e].x = fmaf(qd[dd], kvr[4 * e + 0], acc[e].x);
        acc[e].y = fmaf(qd[dd], kvr[4 * e + 1], acc[e].y);
        acc[e].z = fmaf(qd[dd], kvr[4 * e + 2], acc[e].z);
        acc[e].w = fmaf(qd[dd], kvr[4 * e + 3], acc[e].w);
      }
    }
  }

  const float inv = 1.0f / den;
#pragma unroll
  for (int e = 0; e < 16; ++e) {
    acc[e].x *= inv; acc[e].y *= inv; acc[e].z *= inv; acc[e].w *= inv;
  }

  // staged coalesced store: batch bb covers 64 rows written by wave bb
  float* ob = out + ((size_t)bh * kS + (size_t)rowblk * 256) * kD;
  const int wid = tid >> 6, l = tid & 63;
  for (int bb = 0; bb < 4; ++bb) {
    if (wid == bb) {
#pragma unroll
      for (int e = 0; e < 16; ++e) *(float4*)&ost[l * 68 + 4 * e] = acc[e];
    }
    __syncthreads();
#pragma unroll
    for (int jj = 0; jj < 4; ++jj) {
      const int g = tid + 256 * jj;
      const int r = g >> 4, c = g & 15;
      *(float4*)&ob[(size_t)(bb * 64 + r) * kD + 4 * c] =
          *(const float4*)&ost[r * 68 + 4 * c];
    }
    __syncthreads();
  }
}

extern "C" void kernel_launch(void* const* d_in, const int* in_sizes, int n_in,
                              void* d_out, int out_size, void* d_ws, size_t ws_size,
                              hipStream_t stream) {
  const float* query = (const float*)d_in[0];
  const float* key   = (const float*)d_in[1];
  const float* value = (const float*)d_in[2];
  const float* mask  = (const float*)d_in[3];
  float* outp = (float*)d_out;

  // CH1 = S-chunks per bh; 4 wave-segments per chunk. Pick largest that fits ws.
  auto need = [](int ch1) -> size_t {
    return (size_t)(kBH * 4 * ch1 + kBH) * SEG * sizeof(float);
  };
  int CH1 = 2;                                  // 9.6 MB, known-safe floor
  if (ws_size >= need(8)) CH1 = 8;              // 35.2 MB, 512 blocks (2/CU)
  else if (ws_size >= need(4)) CH1 = 4;         // 18.1 MB

  float* P = (float*)d_ws;                      // kBH*4*CH1 segments
  float* R = P + (size_t)kBH * 4 * CH1 * SEG;   // kBH segments (natural layout)

  hipLaunchKernelGGL(pa_kv_partial, dim3(kBH * CH1), dim3(256), 0, stream,
                     key, value, mask, P, CH1);
  hipLaunchKernelGGL(pa_reduce, dim3((kBH * F4PS + 255) / 256), dim3(256), 0, stream,
                     P, R, 4 * CH1);
  hipLaunchKernelGGL(pa_out, dim3(kBH * 16), dim3(256), 0, stream,
                     query, R, outp);
}